// Round 1
// baseline (4309.325 us; speedup 1.0000x reference)
//
#include <hip/hip_runtime.h>
#include <hip/hip_bf16.h>

// GCN: h = (0.5A)^2 x ; h = relu(h W1 + b1) ; h = (0.5A)^2 h ; h = h W2 + b2
// Algebraic rewrite: (0.5A)^2 (relu(...)) W2 + b2 == (0.5A)^2 (relu(...) W2) + b2
// so W2 is fused into the middle dense kernel and b2 into d_out's init.

#define N_NODES 100000
#define N_EDGES 1600000

// ---------------- SpMM scatter-atomic kernel ----------------
// D = CHUNKS*4 features. Thread i handles (edge = i/CHUNKS, 4-feature chunk
// i%CHUNKS). Consecutive threads of one edge read a contiguous 16B*CHUNKS
// span of h[col] (coalesced) and atomically add into out[row].
template <int CHUNKS>
__global__ void spmm_kernel(const float* __restrict__ h,
                            const float* __restrict__ edge_val,
                            const int* __restrict__ edge_row,
                            const int* __restrict__ edge_col,
                            float* __restrict__ out, int E) {
    constexpr int D = CHUNKS * 4;
    long long idx = (long long)blockIdx.x * blockDim.x + threadIdx.x;
    long long total = (long long)E * CHUNKS;
    long long stride = (long long)gridDim.x * blockDim.x;
    for (long long i = idx; i < total; i += stride) {
        int e = (int)(i >> (CHUNKS == 8 ? 3 : 4));
        int c = (int)(i & (CHUNKS - 1));
        float v = 0.5f * edge_val[e];
        int r = edge_row[e];
        int cc = edge_col[e];
        float4 hv = reinterpret_cast<const float4*>(h + (long long)cc * D)[c];
        float* op = out + (long long)r * D + c * 4;
        atomicAdd(op + 0, v * hv.x);
        atomicAdd(op + 1, v * hv.y);
        atomicAdd(op + 2, v * hv.z);
        atomicAdd(op + 3, v * hv.w);
    }
}

// ---------------- fused dense: out = relu(h@W1 + b1) @ W2 ----------------
// One wave (64 lanes) per row. Lane j owns output feature j.
__global__ void linear_fused_kernel(const float* __restrict__ h,
                                    const float* __restrict__ W1,  // [32,64]
                                    const float* __restrict__ b1,  // [64]
                                    const float* __restrict__ W2,  // [64,64]
                                    float* __restrict__ out, int N) {
    __shared__ float sW1[32 * 64];
    __shared__ float sW2[64 * 64];
    int tid = threadIdx.x;
    for (int i = tid; i < 32 * 64; i += blockDim.x) sW1[i] = W1[i];
    for (int i = tid; i < 64 * 64; i += blockDim.x) sW2[i] = W2[i];
    __syncthreads();

    int lane = tid & 63;
    int wave = tid >> 6;
    int wavesPerBlock = blockDim.x >> 6;
    int row0 = blockIdx.x * wavesPerBlock + wave;
    int rstride = gridDim.x * wavesPerBlock;

    for (int r = row0; r < N; r += rstride) {
        const float* hr = h + (long long)r * 32;
        float hval = (lane < 32) ? hr[lane] : 0.0f;
        float u = b1[lane];
#pragma unroll
        for (int k = 0; k < 32; k++) {
            u = fmaf(__shfl(hval, k), sW1[k * 64 + lane], u);
        }
        u = fmaxf(u, 0.0f);
        float v = 0.0f;
#pragma unroll
        for (int k = 0; k < 64; k++) {
            v = fmaf(__shfl(u, k), sW2[k * 64 + lane], v);
        }
        out[(long long)r * 64 + lane] = v;
    }
}

// ---------------- init d_out with broadcast bias b2 ----------------
__global__ void bias_init_kernel(float* __restrict__ out,
                                 const float* __restrict__ b2, int total) {
    int i = blockIdx.x * blockDim.x + threadIdx.x;
    if (i < total) out[i] = b2[i & 63];
}

extern "C" void kernel_launch(void* const* d_in, const int* in_sizes, int n_in,
                              void* d_out, int out_size, void* d_ws, size_t ws_size,
                              hipStream_t stream) {
    const float* x        = (const float*)d_in[0];
    const float* edge_val = (const float*)d_in[1];
    const int*   edge_row = (const int*)d_in[2];
    const int*   edge_col = (const int*)d_in[3];
    const float* W1       = (const float*)d_in[4];
    const float* b1       = (const float*)d_in[5];
    const float* W2       = (const float*)d_in[6];
    const float* b2       = (const float*)d_in[7];
    float* out = (float*)d_out;

    const int N = in_sizes[0] / 32;   // 100000
    const int E = in_sizes[1];        // 1600000

    float* R1 = (float*)d_ws;                    // N*64 floats
    float* R2 = R1 + (size_t)N * 64;             // N*64 floats

    const int BLK = 256;
    // grid sizes (exact cover)
    long long w32 = (long long)E * 8;
    long long w64 = (long long)E * 16;
    int g32 = (int)((w32 + BLK - 1) / BLK);
    int g64 = (int)((w64 + BLK - 1) / BLK);

    // t0 = spmm32(x) -> R1
    hipMemsetAsync(R1, 0, (size_t)N * 32 * sizeof(float), stream);
    spmm_kernel<8><<<g32, BLK, 0, stream>>>(x, edge_val, edge_row, edge_col, R1, E);

    // t1 = spmm32(t0) -> R2
    hipMemsetAsync(R2, 0, (size_t)N * 32 * sizeof(float), stream);
    spmm_kernel<8><<<g32, BLK, 0, stream>>>(R1, edge_val, edge_row, edge_col, R2, E);

    // t2 = relu(t1@W1+b1)@W2 -> R1   [N,64]
    {
        int wavesPerBlock = BLK / 64;
        int grid = (N + wavesPerBlock - 1) / wavesPerBlock;
        linear_fused_kernel<<<grid, BLK, 0, stream>>>(R2, W1, b1, W2, R1, N);
    }

    // t3 = spmm64(t2) -> R2
    hipMemsetAsync(R2, 0, (size_t)N * 64 * sizeof(float), stream);
    spmm_kernel<16><<<g64, BLK, 0, stream>>>(R1, edge_val, edge_row, edge_col, R2, E);

    // out = b2 (broadcast), then out += spmm64(t3)
    {
        int total = N * 64;
        bias_init_kernel<<<(total + BLK - 1) / BLK, BLK, 0, stream>>>(out, b2, total);
    }
    spmm_kernel<16><<<g64, BLK, 0, stream>>>(R2, edge_val, edge_row, edge_col, out, E);
}

// Round 2
// 710.788 us; speedup vs baseline: 6.0627x; 6.0627x over previous
//
#include <hip/hip_runtime.h>
#include <hip/hip_bf16.h>

// GCN: h = (0.5A)^2 x ; h = relu(h W1 + b1) ; h = (0.5A)^2 h ; h = h W2 + b2
// Rewrites:
//  - (0.5A)^2 (relu(...)) W2 + b2 == (0.5A)^2 (relu(...) W2) + b2  (W2 fused into
//    dense kernel, b2 into final spmm epilogue)
//  - all SpMMs via on-device-built CSR, gather-side, ZERO float atomics
//    (round-1 scatter-atomic version was atomic-RMW bound: WRITE_SIZE 1.6 GB/dispatch)
// Buffer plan (ping-pong, d_out used as scratch):
//  s1 spmm32: x -> d_out          (t0, N*32)
//  s2 spmm32: d_out -> B(ws)      (t1, N*32)
//  s3 dense : B -> d_out          (t2 = relu(t1@W1+b1)@W2, N*64)
//  s4 spmm64: d_out -> B          (t3, N*64)
//  s5 spmm64: B -> d_out (+b2)    (final)

#define SCAN_CHUNK 1024

// ---------------- CSR build ----------------
__global__ void hist_kernel(const int* __restrict__ er, int E, int* __restrict__ cnt) {
    int i = blockIdx.x * blockDim.x + threadIdx.x;
    int stride = gridDim.x * blockDim.x;
    for (; i < E; i += stride) atomicAdd(&cnt[er[i]], 1);
}

__global__ void scan_pass1(const int* __restrict__ cnt, int N,
                           int* __restrict__ excl, int* __restrict__ blockSums) {
    __shared__ int sdata[256];
    int t = threadIdx.x;
    int base = blockIdx.x * SCAN_CHUNK + t * 4;
    int v0 = (base + 0 < N) ? cnt[base + 0] : 0;
    int v1 = (base + 1 < N) ? cnt[base + 1] : 0;
    int v2 = (base + 2 < N) ? cnt[base + 2] : 0;
    int v3 = (base + 3 < N) ? cnt[base + 3] : 0;
    int tsum = v0 + v1 + v2 + v3;
    sdata[t] = tsum;
    __syncthreads();
    for (int off = 1; off < 256; off <<= 1) {
        int x = (t >= off) ? sdata[t - off] : 0;
        __syncthreads();
        sdata[t] += x;
        __syncthreads();
    }
    int texcl = sdata[t] - tsum;  // exclusive prefix of this thread's 4
    if (t == 255) blockSums[blockIdx.x] = sdata[255];
    if (base + 0 < N) excl[base + 0] = texcl;
    if (base + 1 < N) excl[base + 1] = texcl + v0;
    if (base + 2 < N) excl[base + 2] = texcl + v0 + v1;
    if (base + 3 < N) excl[base + 3] = texcl + v0 + v1 + v2;
}

__global__ void scan_pass2(int* blockSums, int nblocks) {
    if (threadIdx.x == 0 && blockIdx.x == 0) {
        int acc = 0;
        for (int i = 0; i < nblocks; i++) { int s = blockSums[i]; blockSums[i] = acc; acc += s; }
    }
}

__global__ void scan_pass3(int* __restrict__ row_ptr, const int* __restrict__ blockOff,
                           int* __restrict__ wp, int N, int E) {
    int i = blockIdx.x * blockDim.x + threadIdx.x;
    if (i < N) {
        int v = row_ptr[i] + blockOff[i / SCAN_CHUNK];
        row_ptr[i] = v;
        wp[i] = v;
    }
    if (i == 0) row_ptr[N] = E;
}

__global__ void scatter_kernel(const int* __restrict__ er, const int* __restrict__ ec,
                               const float* __restrict__ ev, int E,
                               int* __restrict__ wp, int* __restrict__ col_s,
                               float* __restrict__ val_s) {
    int i = blockIdx.x * blockDim.x + threadIdx.x;
    int stride = gridDim.x * blockDim.x;
    for (; i < E; i += stride) {
        int r = er[i];
        int p = atomicAdd(&wp[r], 1);
        col_s[p] = ec[i];
        val_s[p] = 0.5f * ev[i];  // fold FACTOR once; used by all 4 spmms
    }
}

// ---------------- CSR SpMM, gather-side, no atomics ----------------
// D/4 lanes own one output row; each lane owns one float4 feature chunk.
template <int D>
__global__ void spmm_csr_kernel(const float* __restrict__ h,
                                const int* __restrict__ row_ptr,
                                const int* __restrict__ col_s,
                                const float* __restrict__ val_s,
                                float* __restrict__ out,
                                const float* __restrict__ bias,  // nullable
                                int N) {
    constexpr int LPR = D / 4;
    int gid = blockIdx.x * blockDim.x + threadIdx.x;
    int row = gid / LPR;
    int sub = gid % LPR;
    if (row >= N) return;
    int start = row_ptr[row];
    int end   = row_ptr[row + 1];
    float4 acc = make_float4(0.f, 0.f, 0.f, 0.f);
    int j = start;
    int c = 0; float v = 0.f;
    if (j < end) { c = col_s[j]; v = val_s[j]; }
    while (j < end) {
        int jn = j + 1;                     // 1-deep prefetch of edge metadata
        int cn = 0; float vn = 0.f;
        if (jn < end) { cn = col_s[jn]; vn = val_s[jn]; }
        float4 hv = reinterpret_cast<const float4*>(h + (long long)c * D)[sub];
        acc.x = fmaf(v, hv.x, acc.x);
        acc.y = fmaf(v, hv.y, acc.y);
        acc.z = fmaf(v, hv.z, acc.z);
        acc.w = fmaf(v, hv.w, acc.w);
        c = cn; v = vn; j = jn;
    }
    if (bias) {
        acc.x += bias[sub * 4 + 0];
        acc.y += bias[sub * 4 + 1];
        acc.z += bias[sub * 4 + 2];
        acc.w += bias[sub * 4 + 3];
    }
    reinterpret_cast<float4*>(out + (long long)row * D)[sub] = acc;
}

// ---------------- fused dense: out = relu(h@W1 + b1) @ W2 ----------------
__global__ void linear_fused_kernel(const float* __restrict__ h,
                                    const float* __restrict__ W1,  // [32,64]
                                    const float* __restrict__ b1,  // [64]
                                    const float* __restrict__ W2,  // [64,64]
                                    float* __restrict__ out, int N) {
    __shared__ float sW1[32 * 64];
    __shared__ float sW2[64 * 64];
    int tid = threadIdx.x;
    for (int i = tid; i < 32 * 64; i += blockDim.x) sW1[i] = W1[i];
    for (int i = tid; i < 64 * 64; i += blockDim.x) sW2[i] = W2[i];
    __syncthreads();

    int lane = tid & 63;
    int wave = tid >> 6;
    int wavesPerBlock = blockDim.x >> 6;
    int row0 = blockIdx.x * wavesPerBlock + wave;
    int rstride = gridDim.x * wavesPerBlock;

    for (int r = row0; r < N; r += rstride) {
        const float* hr = h + (long long)r * 32;
        float hval = (lane < 32) ? hr[lane] : 0.0f;
        float u = b1[lane];
#pragma unroll
        for (int k = 0; k < 32; k++) u = fmaf(__shfl(hval, k), sW1[k * 64 + lane], u);
        u = fmaxf(u, 0.0f);
        float v = 0.0f;
#pragma unroll
        for (int k = 0; k < 64; k++) v = fmaf(__shfl(u, k), sW2[k * 64 + lane], v);
        out[(long long)r * 64 + lane] = v;
    }
}

extern "C" void kernel_launch(void* const* d_in, const int* in_sizes, int n_in,
                              void* d_out, int out_size, void* d_ws, size_t ws_size,
                              hipStream_t stream) {
    const float* x        = (const float*)d_in[0];
    const float* edge_val = (const float*)d_in[1];
    const int*   edge_row = (const int*)d_in[2];
    const int*   edge_col = (const int*)d_in[3];
    const float* W1       = (const float*)d_in[4];
    const float* b1       = (const float*)d_in[5];
    const float* W2       = (const float*)d_in[6];
    const float* b2       = (const float*)d_in[7];
    float* out = (float*)d_out;

    const int N = in_sizes[0] / 32;   // 100000
    const int E = in_sizes[1];        // 1600000

    // ws layout
    float* B        = (float*)d_ws;                   // N*64 floats (ping buffer)
    int*   row_ptr  = (int*)(B + (size_t)N * 64);     // N+1
    int*   wp       = row_ptr + (N + 1);              // N (also used as count buf)
    int*   blockSums= wp + N;                         // scan block sums
    int*   col_s    = blockSums + 256;                // E
    float* val_s    = (float*)(col_s + E);            // E

    const int BLK = 256;
    int nScanBlocks = (N + SCAN_CHUNK - 1) / SCAN_CHUNK;

    // ---- CSR build ----
    hipMemsetAsync(wp, 0, (size_t)N * sizeof(int), stream);
    hist_kernel<<<(E + BLK - 1) / BLK, BLK, 0, stream>>>(edge_row, E, wp);
    scan_pass1<<<nScanBlocks, 256, 0, stream>>>(wp, N, row_ptr, blockSums);
    scan_pass2<<<1, 64, 0, stream>>>(blockSums, nScanBlocks);
    scan_pass3<<<(N + BLK - 1) / BLK, BLK, 0, stream>>>(row_ptr, blockSums, wp, N, E);
    scatter_kernel<<<(E + BLK - 1) / BLK, BLK, 0, stream>>>(edge_row, edge_col, edge_val,
                                                            E, wp, col_s, val_s);

    // ---- pipeline ----
    int g32 = ((N * 8)  + BLK - 1) / BLK;   // D=32: 8 lanes/row
    int g64 = ((N * 16) + BLK - 1) / BLK;   // D=64: 16 lanes/row

    // s1: t0 = spmm32(x) -> d_out
    spmm_csr_kernel<32><<<g32, BLK, 0, stream>>>(x, row_ptr, col_s, val_s, out, nullptr, N);
    // s2: t1 = spmm32(t0) -> B
    spmm_csr_kernel<32><<<g32, BLK, 0, stream>>>(out, row_ptr, col_s, val_s, B, nullptr, N);
    // s3: t2 = relu(t1@W1+b1)@W2 -> d_out
    {
        int wavesPerBlock = BLK / 64;
        int grid = (N + wavesPerBlock - 1) / wavesPerBlock;
        linear_fused_kernel<<<grid, BLK, 0, stream>>>(B, W1, b1, W2, out, N);
    }
    // s4: t3 = spmm64(t2) -> B
    spmm_csr_kernel<64><<<g64, BLK, 0, stream>>>(out, row_ptr, col_s, val_s, B, nullptr, N);
    // s5: out = spmm64(t3) + b2 -> d_out
    spmm_csr_kernel<64><<<g64, BLK, 0, stream>>>(B, row_ptr, col_s, val_s, out, b2, N);
}

// Round 3
// 516.608 us; speedup vs baseline: 8.3416x; 1.3759x over previous
//
#include <hip/hip_runtime.h>
#include <hip/hip_bf16.h>

// GCN: h = (0.5A)^2 x ; h = relu(h W1 + b1) ; h = (0.5A)^2 h ; h = h W2 + b2
// Rewrites:
//  - (0.5A)^2 (relu(...)) W2 + b2 == (0.5A)^2 (relu(...) W2) + b2
//  - SpMMs via on-device CSR, gather-side, zero float atomics
//  - dense layer: row-per-lane (wave-uniform W reads; round-2 shuffle version
//    was LDS-pipe bound at 221 us / 21% VALUBusy)
// Buffer plan (ping-pong, d_out used as scratch):
//  s1 spmm32: x -> d_out ; s2 spmm32: d_out -> B ; s3 dense: B -> d_out
//  s4 spmm64: d_out -> B ; s5 spmm64: B -> d_out (+b2)

#define SCAN_CHUNK 1024

// ---------------- CSR build ----------------
__global__ void hist_kernel(const int* __restrict__ er, int E, int* __restrict__ cnt) {
    int i = blockIdx.x * blockDim.x + threadIdx.x;
    int stride = gridDim.x * blockDim.x;
    for (; i < E; i += stride) atomicAdd(&cnt[er[i]], 1);
}

__global__ void scan_pass1(const int* __restrict__ cnt, int N,
                           int* __restrict__ excl, int* __restrict__ blockSums) {
    __shared__ int sdata[256];
    int t = threadIdx.x;
    int base = blockIdx.x * SCAN_CHUNK + t * 4;
    int v0 = (base + 0 < N) ? cnt[base + 0] : 0;
    int v1 = (base + 1 < N) ? cnt[base + 1] : 0;
    int v2 = (base + 2 < N) ? cnt[base + 2] : 0;
    int v3 = (base + 3 < N) ? cnt[base + 3] : 0;
    int tsum = v0 + v1 + v2 + v3;
    sdata[t] = tsum;
    __syncthreads();
    for (int off = 1; off < 256; off <<= 1) {
        int x = (t >= off) ? sdata[t - off] : 0;
        __syncthreads();
        sdata[t] += x;
        __syncthreads();
    }
    int texcl = sdata[t] - tsum;
    if (t == 255) blockSums[blockIdx.x] = sdata[255];
    if (base + 0 < N) excl[base + 0] = texcl;
    if (base + 1 < N) excl[base + 1] = texcl + v0;
    if (base + 2 < N) excl[base + 2] = texcl + v0 + v1;
    if (base + 3 < N) excl[base + 3] = texcl + v0 + v1 + v2;
}

__global__ void scan_pass2(int* blockSums, int nblocks) {
    if (threadIdx.x == 0 && blockIdx.x == 0) {
        int acc = 0;
        for (int i = 0; i < nblocks; i++) { int s = blockSums[i]; blockSums[i] = acc; acc += s; }
    }
}

__global__ void scan_pass3(int* __restrict__ row_ptr, const int* __restrict__ blockOff,
                           int* __restrict__ wp, int N, int E) {
    int i = blockIdx.x * blockDim.x + threadIdx.x;
    if (i < N) {
        int v = row_ptr[i] + blockOff[i / SCAN_CHUNK];
        row_ptr[i] = v;
        wp[i] = v;
    }
    if (i == 0) row_ptr[N] = E;
}

// packed edge: .x = col, .y = bits of (0.5f * val)
__global__ void scatter_kernel(const int* __restrict__ er, const int* __restrict__ ec,
                               const float* __restrict__ ev, int E,
                               int* __restrict__ wp, int2* __restrict__ cv) {
    int i = blockIdx.x * blockDim.x + threadIdx.x;
    int stride = gridDim.x * blockDim.x;
    for (; i < E; i += stride) {
        int r = er[i];
        int p = atomicAdd(&wp[r], 1);
        int2 e;
        e.x = ec[i];
        e.y = __float_as_int(0.5f * ev[i]);
        cv[p] = e;
    }
}

// ---------------- CSR SpMM, gather-side ----------------
// D/4 lanes per output row; lane owns one float4 chunk; 4-deep gather unroll.
template <int D>
__global__ void spmm_csr_kernel(const float* __restrict__ h,
                                const int* __restrict__ row_ptr,
                                const int2* __restrict__ cv,
                                float* __restrict__ out,
                                const float* __restrict__ bias,  // nullable
                                int N) {
    constexpr int LPR = D / 4;
    int gid = blockIdx.x * blockDim.x + threadIdx.x;
    int row = gid / LPR;
    int sub = gid % LPR;
    if (row >= N) return;
    int start = row_ptr[row];
    int end   = row_ptr[row + 1];
    float4 acc = make_float4(0.f, 0.f, 0.f, 0.f);
    int j = start;
    for (; j + 4 <= end; j += 4) {
        int2 e0 = cv[j], e1 = cv[j + 1], e2 = cv[j + 2], e3 = cv[j + 3];
        float4 h0 = reinterpret_cast<const float4*>(h + (long long)e0.x * D)[sub];
        float4 h1 = reinterpret_cast<const float4*>(h + (long long)e1.x * D)[sub];
        float4 h2 = reinterpret_cast<const float4*>(h + (long long)e2.x * D)[sub];
        float4 h3 = reinterpret_cast<const float4*>(h + (long long)e3.x * D)[sub];
        float v0 = __int_as_float(e0.y), v1 = __int_as_float(e1.y);
        float v2 = __int_as_float(e2.y), v3 = __int_as_float(e3.y);
        acc.x = fmaf(v0, h0.x, acc.x); acc.y = fmaf(v0, h0.y, acc.y);
        acc.z = fmaf(v0, h0.z, acc.z); acc.w = fmaf(v0, h0.w, acc.w);
        acc.x = fmaf(v1, h1.x, acc.x); acc.y = fmaf(v1, h1.y, acc.y);
        acc.z = fmaf(v1, h1.z, acc.z); acc.w = fmaf(v1, h1.w, acc.w);
        acc.x = fmaf(v2, h2.x, acc.x); acc.y = fmaf(v2, h2.y, acc.y);
        acc.z = fmaf(v2, h2.z, acc.z); acc.w = fmaf(v2, h2.w, acc.w);
        acc.x = fmaf(v3, h3.x, acc.x); acc.y = fmaf(v3, h3.y, acc.y);
        acc.z = fmaf(v3, h3.z, acc.z); acc.w = fmaf(v3, h3.w, acc.w);
    }
    for (; j < end; j++) {
        int2 e = cv[j];
        float v = __int_as_float(e.y);
        float4 hv = reinterpret_cast<const float4*>(h + (long long)e.x * D)[sub];
        acc.x = fmaf(v, hv.x, acc.x); acc.y = fmaf(v, hv.y, acc.y);
        acc.z = fmaf(v, hv.z, acc.z); acc.w = fmaf(v, hv.w, acc.w);
    }
    if (bias) {
        acc.x += bias[sub * 4 + 0];
        acc.y += bias[sub * 4 + 1];
        acc.z += bias[sub * 4 + 2];
        acc.w += bias[sub * 4 + 3];
    }
    reinterpret_cast<float4*>(out + (long long)row * D)[sub] = acc;
}

// ---------------- fused dense: out = relu(h@W1 + b1) @ W2, row-per-lane ------
// One lane per row. W1/W2 reads are wave-uniform (scalar path, off LDS pipe).
// h staged in per-wave LDS tile (stride 33, conflict-free); u round-trips
// through the same tile XOR-swizzled at stride 64. No __syncthreads needed.
__global__ __launch_bounds__(256) void dense_fused_kernel(
        const float* __restrict__ h,   // [N,32]
        const float* __restrict__ W1,  // [32,64]
        const float* __restrict__ b1,  // [64]
        const float* __restrict__ W2,  // [64,64]
        float* __restrict__ out, int N) {
    __shared__ float buf[4 * 64 * 64];  // 64 KB: per-wave 4096-float tile
    int tid = threadIdx.x;
    int lane = tid & 63;
    int wave = tid >> 6;
    float* wbuf = &buf[wave * 4096];

    int rowbase = blockIdx.x * 256 + wave * 64;
    if (rowbase >= N) return;           // wave-uniform
    int row = rowbase + lane;
    bool valid = row < N;

    // ---- cooperative, coalesced h stage: 64 rows x 32 floats contiguous ----
    {
        const float* src = h + (long long)rowbase * 32;
        int maxf = (N - rowbase) * 32;  // valid floats in this wave's span
#pragma unroll
        for (int i = 0; i < 8; i++) {
            int f = i * 256 + lane * 4;
            int fc = (f + 4 <= maxf) ? f : (maxf >= 4 ? maxf - 4 : 0);
            float4 a = reinterpret_cast<const float4*>(src + fc)[0];
            int r = fc >> 5, k = fc & 31;
            float* dst = wbuf + r * 33 + k;
            dst[0] = a.x; dst[1] = a.y; dst[2] = a.z; dst[3] = a.w;
        }
    }

    // ---- phase 1: u = relu(h @ W1 + b1) ----
    float u[64];
#pragma unroll
    for (int j = 0; j < 64; j++) u[j] = b1[j];
    for (int k = 0; k < 32; k++) {
        float hk = wbuf[lane * 33 + k];
        const float* w1r = W1 + k * 64;
#pragma unroll
        for (int j = 0; j < 64; j++) u[j] = fmaf(hk, w1r[j], u[j]);
    }
#pragma unroll
    for (int j = 0; j < 64; j++) u[j] = fmaxf(u[j], 0.0f);

    // ---- spill u to LDS (XOR swizzle keeps banks conflict-free) ----
#pragma unroll
    for (int j = 0; j < 64; j++) wbuf[lane * 64 + ((j + lane) & 63)] = u[j];

    // ---- phase 2: v = u @ W2 ----
    float v[64];
#pragma unroll
    for (int j = 0; j < 64; j++) v[j] = 0.0f;
    for (int k = 0; k < 64; k++) {
        float uk = wbuf[lane * 64 + ((k + lane) & 63)];
        const float* w2r = W2 + k * 64;
#pragma unroll
        for (int j = 0; j < 64; j++) v[j] = fmaf(uk, w2r[j], v[j]);
    }

    if (valid) {
        float4* op = reinterpret_cast<float4*>(out + (long long)row * 64);
#pragma unroll
        for (int m = 0; m < 16; m++) {
            float4 o;
            o.x = v[m * 4 + 0]; o.y = v[m * 4 + 1];
            o.z = v[m * 4 + 2]; o.w = v[m * 4 + 3];
            op[m] = o;
        }
    }
}

extern "C" void kernel_launch(void* const* d_in, const int* in_sizes, int n_in,
                              void* d_out, int out_size, void* d_ws, size_t ws_size,
                              hipStream_t stream) {
    const float* x        = (const float*)d_in[0];
    const float* edge_val = (const float*)d_in[1];
    const int*   edge_row = (const int*)d_in[2];
    const int*   edge_col = (const int*)d_in[3];
    const float* W1       = (const float*)d_in[4];
    const float* b1       = (const float*)d_in[5];
    const float* W2       = (const float*)d_in[6];
    const float* b2       = (const float*)d_in[7];
    float* out = (float*)d_out;

    const int N = in_sizes[0] / 32;   // 100000
    const int E = in_sizes[1];        // 1600000

    // ws layout
    float* B         = (float*)d_ws;                  // N*64 floats (ping buffer)
    int*   row_ptr   = (int*)(B + (size_t)N * 64);    // N+1
    int*   wp        = row_ptr + (N + 1);             // N
    int*   blockSums = wp + N;                        // 256
    size_t cvOff = (size_t)((char*)(blockSums + 256) - (char*)d_ws);
    cvOff = (cvOff + 7) & ~(size_t)7;
    int2* cv = (int2*)((char*)d_ws + cvOff);          // E packed edges

    const int BLK = 256;
    int nScanBlocks = (N + SCAN_CHUNK - 1) / SCAN_CHUNK;

    // ---- CSR build ----
    hipMemsetAsync(wp, 0, (size_t)N * sizeof(int), stream);
    hist_kernel<<<(E + BLK - 1) / BLK, BLK, 0, stream>>>(edge_row, E, wp);
    scan_pass1<<<nScanBlocks, 256, 0, stream>>>(wp, N, row_ptr, blockSums);
    scan_pass2<<<1, 64, 0, stream>>>(blockSums, nScanBlocks);
    scan_pass3<<<(N + BLK - 1) / BLK, BLK, 0, stream>>>(row_ptr, blockSums, wp, N, E);
    scatter_kernel<<<(E + BLK - 1) / BLK, BLK, 0, stream>>>(edge_row, edge_col, edge_val,
                                                            E, wp, cv);

    // ---- pipeline ----
    int g32 = ((N * 8)  + BLK - 1) / BLK;   // D=32: 8 lanes/row
    int g64 = ((N * 16) + BLK - 1) / BLK;   // D=64: 16 lanes/row

    spmm_csr_kernel<32><<<g32, BLK, 0, stream>>>(x, row_ptr, cv, out, nullptr, N);
    spmm_csr_kernel<32><<<g32, BLK, 0, stream>>>(out, row_ptr, cv, B, nullptr, N);
    dense_fused_kernel<<<(N + 255) / 256, 256, 0, stream>>>(B, W1, b1, W2, out, N);
    spmm_csr_kernel<64><<<g64, BLK, 0, stream>>>(out, row_ptr, cv, B, nullptr, N);
    spmm_csr_kernel<64><<<g64, BLK, 0, stream>>>(B, row_ptr, cv, out, b2, N);
}